// Round 7
// baseline (542.903 us; speedup 1.0000x reference)
//
#include <hip/hip_runtime.h>
#include <cmath>

// Problem constants
#define SS 2048
#define BB 32
#define HH 1024
#define NWAVES 8192  // energy: 2048 blocks * 4 waves

// ---------------------------------------------------------------------------
// K1a: partial u[h] = sum over a 64-wide k-chunk of v[k] * We[k][h]
//      We[k][h] = attn_W[k][HH + h], attn_W row-major (HH, 2*HH)
// grid (4, 16), block 256  -> 64 blocks  [PROVEN round-1/5: memory pattern
// untouched since round-4's unexplained +13us on a reshape]
// ---------------------------------------------------------------------------
__global__ __launch_bounds__(256) void partial_u_kernel(
    const float* __restrict__ W, const float* __restrict__ v,
    float* __restrict__ partial) {
  int h  = blockIdx.x * 256 + threadIdx.x;  // 0..1023
  int k0 = blockIdx.y * 64;
  float acc = 0.f;
#pragma unroll 8
  for (int k = k0; k < k0 + 64; ++k)
    acc += v[k] * W[(size_t)k * (2 * HH) + HH + h];
  partial[blockIdx.y * HH + h] = acc;
}

// K1b: u[h] = sum of 16 partials; ALSO zeroes done[32] tickets for K2
// (spare work on block 0 — no extra dispatch, no change to read pattern)
__global__ __launch_bounds__(256) void reduce_u_kernel(
    const float* __restrict__ partial, float* __restrict__ u,
    int* __restrict__ done) {
  if (blockIdx.x == 0 && threadIdx.x < BB) done[threadIdx.x] = 0;
  int h = blockIdx.x * 256 + threadIdx.x;
  float acc = 0.f;
#pragma unroll
  for (int c = 0; c < 16; ++c) acc += partial[c * HH + h];
  u[h] = acc;
}

// ---------------------------------------------------------------------------
// K2: energy + fused last-arriver softmax.
// Each wave grid-strides 8 rows (row = wave + it*8192), all sharing
// b = wave & 31. After storing its rows: threadfence + ticket. The 256th
// wave for b runs the row softmax (fixed order -> deterministic output).
// No spin-waits: deadlock-free under any scheduling.
// ---------------------------------------------------------------------------
__global__ __launch_bounds__(256) void energy_softmax_kernel(
    const float* __restrict__ enc, const float* __restrict__ u,
    float* __restrict__ out, int* __restrict__ done) {
  int wave = blockIdx.x * 4 + (threadIdx.x >> 6);  // 0..8191
  int lane = threadIdx.x & 63;
  int b_   = wave & (BB - 1);  // all 8 rows of this wave share b

  const float4* u4 = reinterpret_cast<const float4*>(u);
  float4 uv[4];
#pragma unroll
  for (int j = 0; j < 4; ++j) uv[j] = u4[lane + j * 64];

  const float4* base = reinterpret_cast<const float4*>(enc);

  float4 cur[4];
  {
    const float4* e4 = base + (size_t)wave * (HH / 4);
#pragma unroll
    for (int j = 0; j < 4; ++j) cur[j] = e4[lane + j * 64];
  }

#pragma unroll
  for (int it = 0; it < 8; ++it) {
    int row = wave + it * NWAVES;
    float4 nxt[4];
    if (it < 7) {
      const float4* e4 = base + (size_t)(row + NWAVES) * (HH / 4);
#pragma unroll
      for (int j = 0; j < 4; ++j) nxt[j] = e4[lane + j * 64];
    }
    float acc = 0.f;
#pragma unroll
    for (int j = 0; j < 4; ++j)
      acc += cur[j].x * uv[j].x + cur[j].y * uv[j].y +
             cur[j].z * uv[j].z + cur[j].w * uv[j].w;
#pragma unroll
    for (int m = 32; m; m >>= 1) acc += __shfl_xor(acc, m, 64);
    if (lane == 0) {
      int s_ = row >> 5;  // row / BB
      out[(size_t)b_ * SS + s_] = acc;
    }
#pragma unroll
    for (int j = 0; j < 4; ++j) cur[j] = nxt[j];
  }

  // --- last-arriver softmax for batch b_ ---
  __threadfence();  // release our energy stores
  int t = 0;
  if (lane == 0) t = atomicAdd(&done[b_], 1);
  t = __shfl(t, 0, 64);
  if (t == (NWAVES / BB) - 1) {  // 256th (last) wave for this b
    __threadfence();  // acquire others' stores
    float* rowp = out + (size_t)b_ * SS;
    float vals[32];
    float mx = -INFINITY;
#pragma unroll
    for (int i = 0; i < 32; ++i) {
      vals[i] = rowp[lane + i * 64];
      mx = fmaxf(mx, vals[i]);
    }
#pragma unroll
    for (int m = 32; m; m >>= 1) mx = fmaxf(mx, __shfl_xor(mx, m, 64));
    float sum = 0.f;
#pragma unroll
    for (int i = 0; i < 32; ++i) {
      vals[i] = expf(vals[i] - mx);
      sum += vals[i];
    }
#pragma unroll
    for (int m = 32; m; m >>= 1) sum += __shfl_xor(sum, m, 64);
    float inv = 1.0f / sum;
#pragma unroll
    for (int i = 0; i < 32; ++i) rowp[lane + i * 64] = vals[i] * inv;
  }
}

extern "C" void kernel_launch(void* const* d_in, const int* in_sizes, int n_in,
                              void* d_out, int out_size, void* d_ws, size_t ws_size,
                              hipStream_t stream) {
  const float* enc = (const float*)d_in[0];   // (S,B,H)
  // d_in[1] rnn_hidden, d_in[3] attn_b: cancel under softmax (shift-invariant)
  const float* W = (const float*)d_in[2];     // (H, 2H)
  const float* v = (const float*)d_in[4];     // (1, H)
  float* out = (float*)d_out;                 // (B,1,S) = B*S floats

  float* u       = (float*)d_ws;                       // bytes [0, 4096)
  float* partial = (float*)d_ws + HH;                  // bytes [4096, 69632)
  int*   done    = (int*)((char*)d_ws + 69632);        // bytes [69632, 69760)

  partial_u_kernel<<<dim3(4, 16), 256, 0, stream>>>(W, v, partial);
  reduce_u_kernel<<<4, 256, 0, stream>>>(partial, u, done);
  energy_softmax_kernel<<<NWAVES / 4, 256, 0, stream>>>(enc, u, out, done);
}

// Round 8
// 70.084 us; speedup vs baseline: 7.7464x; 7.7464x over previous
//
#include <hip/hip_runtime.h>
#include <cmath>

// Problem constants
#define SS 2048
#define BB 32
#define HH 1024

// ---------------------------------------------------------------------------
// K1a: partial u[h] = sum over a 64-wide k-chunk of v[k] * We[k][h]
//      We[k][h] = attn_W[k][HH + h], attn_W row-major (HH, 2*HH)
// grid (4, 16), block 256 -> 64 blocks. ROUND-8 single change: FULL unroll
// (was unroll 8) so the compiler can put ~32+ independent 4B loads in flight
// before the first s_waitcnt -> fewer serial HBM-latency rounds.
// ---------------------------------------------------------------------------
__global__ __launch_bounds__(256) void partial_u_kernel(
    const float* __restrict__ W, const float* __restrict__ v,
    float* __restrict__ partial) {
  int h  = blockIdx.x * 256 + threadIdx.x;  // 0..1023
  int k0 = blockIdx.y * 64;
  float acc = 0.f;
#pragma unroll
  for (int k = k0; k < k0 + 64; ++k)
    acc += v[k] * W[(size_t)k * (2 * HH) + HH + h];
  partial[blockIdx.y * HH + h] = acc;
}

// K1b: u[h] = sum of 16 partials (deterministic, no atomics)
__global__ __launch_bounds__(256) void reduce_u_kernel(
    const float* __restrict__ partial, float* __restrict__ u) {
  int h = blockIdx.x * 256 + threadIdx.x;
  float acc = 0.f;
#pragma unroll
  for (int c = 0; c < 16; ++c) acc += partial[c * HH + h];
  u[h] = acc;
}

// ---------------------------------------------------------------------------
// K2: energy[b*S + s] = dot(enc[s,b,:], u)   -- the 256 MiB streaming kernel
// PROVEN round-1/5 version (53.0 us): one wave per row, 2048 blocks,
// plain float4 loads. At ~6.2 TB/s read = 98% of measured ceiling.
// ---------------------------------------------------------------------------
__global__ __launch_bounds__(256) void energy_kernel(
    const float* __restrict__ enc, const float* __restrict__ u,
    float* __restrict__ energy) {
  int wid  = blockIdx.x * 4 + (threadIdx.x >> 6);  // 0 .. S*B-1  ( = s*B + b )
  int lane = threadIdx.x & 63;
  const float4* e4 = reinterpret_cast<const float4*>(enc) + (size_t)wid * (HH / 4);
  const float4* u4 = reinterpret_cast<const float4*>(u);
  float acc = 0.f;
#pragma unroll
  for (int j = 0; j < 4; ++j) {
    float4 ev = e4[lane + j * 64];
    float4 uv = u4[lane + j * 64];
    acc += ev.x * uv.x + ev.y * uv.y + ev.z * uv.z + ev.w * uv.w;
  }
#pragma unroll
  for (int m = 32; m; m >>= 1) acc += __shfl_xor(acc, m, 64);
  if (lane == 0) {
    int s_ = wid / BB;
    int b_ = wid % BB;
    energy[(size_t)b_ * SS + s_] = acc;
  }
}

// ---------------------------------------------------------------------------
// K3: in-place row softmax on d_out: 32 rows of 2048. One block per row.
// ---------------------------------------------------------------------------
__global__ __launch_bounds__(256) void softmax_kernel(float* __restrict__ e) {
  int b = blockIdx.x;
  float* row = e + (size_t)b * SS;
  int tid  = threadIdx.x;
  int lane = tid & 63;
  int wv   = tid >> 6;

  float vals[8];
  float mx = -INFINITY;
#pragma unroll
  for (int i = 0; i < 8; ++i) {
    vals[i] = row[tid + i * 256];
    mx = fmaxf(mx, vals[i]);
  }
#pragma unroll
  for (int m = 32; m; m >>= 1) mx = fmaxf(mx, __shfl_xor(mx, m, 64));

  __shared__ float red_max[4];
  __shared__ float red_sum[4];
  if (lane == 0) red_max[wv] = mx;
  __syncthreads();
  mx = fmaxf(fmaxf(red_max[0], red_max[1]), fmaxf(red_max[2], red_max[3]));

  float sum = 0.f;
#pragma unroll
  for (int i = 0; i < 8; ++i) {
    vals[i] = expf(vals[i] - mx);
    sum += vals[i];
  }
#pragma unroll
  for (int m = 32; m; m >>= 1) sum += __shfl_xor(sum, m, 64);
  if (lane == 0) red_sum[wv] = sum;
  __syncthreads();
  sum = red_sum[0] + red_sum[1] + red_sum[2] + red_sum[3];

  float inv = 1.0f / sum;
#pragma unroll
  for (int i = 0; i < 8; ++i) row[tid + i * 256] = vals[i] * inv;
}

extern "C" void kernel_launch(void* const* d_in, const int* in_sizes, int n_in,
                              void* d_out, int out_size, void* d_ws, size_t ws_size,
                              hipStream_t stream) {
  const float* enc = (const float*)d_in[0];   // (S,B,H)
  // d_in[1] rnn_hidden, d_in[3] attn_b: cancel under softmax (shift-invariant)
  const float* W = (const float*)d_in[2];     // (H, 2H)
  const float* v = (const float*)d_in[4];     // (1, H)
  float* out = (float*)d_out;                 // (B,1,S) = B*S floats

  float* u       = (float*)d_ws;              // 4 KB
  float* partial = (float*)d_ws + HH;         // 64 KB

  partial_u_kernel<<<dim3(4, 16), 256, 0, stream>>>(W, v, partial);
  reduce_u_kernel<<<4, 256, 0, stream>>>(partial, u);
  energy_kernel<<<(SS * BB) / 4, 256, 0, stream>>>(enc, u, out);
  softmax_kernel<<<BB, 256, 0, stream>>>(out);
}

// Round 9
// 54.220 us; speedup vs baseline: 10.0130x; 1.2926x over previous
//
#include <hip/hip_runtime.h>
#include <cmath>

// Problem constants
#define SS 2048
#define BB 32
#define HH 1024

// ---------------------------------------------------------------------------
// K1a: partial u[h] over 16-wide k-chunks: partial[c][h] = sum_{k in c}
//      v[k] * We[k][h],  We[k][h] = attn_W[k][HH + h]
// grid (4, 64) = 256 blocks. 16-iter full unroll -> only 16 outstanding
// scalar loads (16 result VGPRs) — below the register-blowup cliff that
// killed R4 (reduce 64-unroll) and R8 (partial 64-unroll).
// ---------------------------------------------------------------------------
__global__ __launch_bounds__(256) void partial_u_kernel(
    const float* __restrict__ W, const float* __restrict__ v,
    float* __restrict__ partial) {
  int h  = blockIdx.x * 256 + threadIdx.x;  // 0..1023
  int k0 = blockIdx.y * 16;
  float acc = 0.f;
#pragma unroll
  for (int k = k0; k < k0 + 16; ++k)
    acc += v[k] * W[(size_t)k * (2 * HH) + HH + h];
  partial[blockIdx.y * HH + h] = acc;
}

// K1b: u[h] = sum of 64 partials. unroll 8 (NOT full): 8 outstanding loads,
// no register blowup; partial is L2-resident so 8 latency rounds are cheap.
__global__ __launch_bounds__(256) void reduce_u_kernel(
    const float* __restrict__ partial, float* __restrict__ u) {
  int h = blockIdx.x * 256 + threadIdx.x;
  float acc = 0.f;
#pragma unroll 8
  for (int c = 0; c < 64; ++c) acc += partial[c * HH + h];
  u[h] = acc;
}

// ---------------------------------------------------------------------------
// K2: energy[b*S + s] = dot(enc[s,b,:], u)  [PROVEN 53.0us version — R1/R5,
// byte-identical: one wave per row, 2048 blocks, plain float4 loads,
// ~6.2 TB/s = 98% of measured read ceiling]
// ---------------------------------------------------------------------------
__global__ __launch_bounds__(256) void energy_kernel(
    const float* __restrict__ enc, const float* __restrict__ u,
    float* __restrict__ energy) {
  int wid  = blockIdx.x * 4 + (threadIdx.x >> 6);  // 0 .. S*B-1  ( = s*B + b )
  int lane = threadIdx.x & 63;
  const float4* e4 = reinterpret_cast<const float4*>(enc) + (size_t)wid * (HH / 4);
  const float4* u4 = reinterpret_cast<const float4*>(u);
  float acc = 0.f;
#pragma unroll
  for (int j = 0; j < 4; ++j) {
    float4 ev = e4[lane + j * 64];
    float4 uv = u4[lane + j * 64];
    acc += ev.x * uv.x + ev.y * uv.y + ev.z * uv.z + ev.w * uv.w;
  }
#pragma unroll
  for (int m = 32; m; m >>= 1) acc += __shfl_xor(acc, m, 64);
  if (lane == 0) {
    int s_ = wid / BB;
    int b_ = wid % BB;
    energy[(size_t)b_ * SS + s_] = acc;
  }
}

// ---------------------------------------------------------------------------
// K3: in-place row softmax on d_out [PROVEN — byte-identical to R1/R5]
// ---------------------------------------------------------------------------
__global__ __launch_bounds__(256) void softmax_kernel(float* __restrict__ e) {
  int b = blockIdx.x;
  float* row = e + (size_t)b * SS;
  int tid  = threadIdx.x;
  int lane = tid & 63;
  int wv   = tid >> 6;

  float vals[8];
  float mx = -INFINITY;
#pragma unroll
  for (int i = 0; i < 8; ++i) {
    vals[i] = row[tid + i * 256];
    mx = fmaxf(mx, vals[i]);
  }
#pragma unroll
  for (int m = 32; m; m >>= 1) mx = fmaxf(mx, __shfl_xor(mx, m, 64));

  __shared__ float red_max[4];
  __shared__ float red_sum[4];
  if (lane == 0) red_max[wv] = mx;
  __syncthreads();
  mx = fmaxf(fmaxf(red_max[0], red_max[1]), fmaxf(red_max[2], red_max[3]));

  float sum = 0.f;
#pragma unroll
  for (int i = 0; i < 8; ++i) {
    vals[i] = expf(vals[i] - mx);
    sum += vals[i];
  }
#pragma unroll
  for (int m = 32; m; m >>= 1) sum += __shfl_xor(sum, m, 64);
  if (lane == 0) red_sum[wv] = sum;
  __syncthreads();
  sum = red_sum[0] + red_sum[1] + red_sum[2] + red_sum[3];

  float inv = 1.0f / sum;
#pragma unroll
  for (int i = 0; i < 8; ++i) row[tid + i * 256] = vals[i] * inv;
}

extern "C" void kernel_launch(void* const* d_in, const int* in_sizes, int n_in,
                              void* d_out, int out_size, void* d_ws, size_t ws_size,
                              hipStream_t stream) {
  const float* enc = (const float*)d_in[0];   // (S,B,H)
  // d_in[1] rnn_hidden, d_in[3] attn_b: cancel under softmax (shift-invariant)
  const float* W = (const float*)d_in[2];     // (H, 2H)
  const float* v = (const float*)d_in[4];     // (1, H)
  float* out = (float*)d_out;                 // (B,1,S) = B*S floats

  float* u       = (float*)d_ws;              // 4 KB
  float* partial = (float*)d_ws + HH;         // 256 KB

  partial_u_kernel<<<dim3(4, 64), 256, 0, stream>>>(W, v, partial);
  reduce_u_kernel<<<4, 256, 0, stream>>>(partial, u);
  energy_kernel<<<(SS * BB) / 4, 256, 0, stream>>>(enc, u, out);
  softmax_kernel<<<BB, 256, 0, stream>>>(out);
}

// Round 10
// 52.917 us; speedup vs baseline: 10.2595x; 1.0246x over previous
//
#include <hip/hip_runtime.h>
#include <cmath>

// ============================================================================
// TERMINAL SUBMISSION — byte-identical to the proven R1/R5 artifact
// (52.95 / 53.0 us, A/A reproducible to ±0.1%).
//
// Structure: softmax(energy) where energy[b,s] = dot(enc[s,b,:], u),
// u = We^T v. rnn_hidden / attn_b / Wh cancel under softmax shift-invariance.
//
// Evidence trail (9 rounds):
//  - energy stream (268 MB) runs ~6.2-6.5 TB/s = at/above m13 measured copy
//    ceiling; persistent/pipelined variant (R6) identical -> HBM-saturated.
//  - u-phase/softmax/gaps ~10us: all redesigns regressed or were neutral
//    (R3 +8, R4 +13, R8 +17, R9 +1.2, R7 fence-fusion +490).
//  - >=64-iteration full unrolls of load loops cause VGPR blowup on this
//    compiler: keep outstanding loads <= 16 per thread.
// ============================================================================
#define SS 2048
#define BB 32
#define HH 1024

__global__ __launch_bounds__(256) void partial_u_kernel(
    const float* __restrict__ W, const float* __restrict__ v,
    float* __restrict__ partial) {
  int h  = blockIdx.x * 256 + threadIdx.x;  // 0..1023
  int k0 = blockIdx.y * 64;
  float acc = 0.f;
#pragma unroll 8
  for (int k = k0; k < k0 + 64; ++k)
    acc += v[k] * W[(size_t)k * (2 * HH) + HH + h];
  partial[blockIdx.y * HH + h] = acc;
}

__global__ __launch_bounds__(256) void reduce_u_kernel(
    const float* __restrict__ partial, float* __restrict__ u) {
  int h = blockIdx.x * 256 + threadIdx.x;
  float acc = 0.f;
#pragma unroll
  for (int c = 0; c < 16; ++c) acc += partial[c * HH + h];
  u[h] = acc;
}

__global__ __launch_bounds__(256) void energy_kernel(
    const float* __restrict__ enc, const float* __restrict__ u,
    float* __restrict__ energy) {
  int wid  = blockIdx.x * 4 + (threadIdx.x >> 6);  // 0 .. S*B-1  ( = s*B + b )
  int lane = threadIdx.x & 63;
  const float4* e4 = reinterpret_cast<const float4*>(enc) + (size_t)wid * (HH / 4);
  const float4* u4 = reinterpret_cast<const float4*>(u);
  float acc = 0.f;
#pragma unroll
  for (int j = 0; j < 4; ++j) {
    float4 ev = e4[lane + j * 64];
    float4 uv = u4[lane + j * 64];
    acc += ev.x * uv.x + ev.y * uv.y + ev.z * uv.z + ev.w * uv.w;
  }
#pragma unroll
  for (int m = 32; m; m >>= 1) acc += __shfl_xor(acc, m, 64);
  if (lane == 0) {
    int s_ = wid / BB;
    int b_ = wid % BB;
    energy[(size_t)b_ * SS + s_] = acc;
  }
}

__global__ __launch_bounds__(256) void softmax_kernel(float* __restrict__ e) {
  int b = blockIdx.x;
  float* row = e + (size_t)b * SS;
  int tid  = threadIdx.x;
  int lane = tid & 63;
  int wv   = tid >> 6;

  float vals[8];
  float mx = -INFINITY;
#pragma unroll
  for (int i = 0; i < 8; ++i) {
    vals[i] = row[tid + i * 256];
    mx = fmaxf(mx, vals[i]);
  }
#pragma unroll
  for (int m = 32; m; m >>= 1) mx = fmaxf(mx, __shfl_xor(mx, m, 64));

  __shared__ float red_max[4];
  __shared__ float red_sum[4];
  if (lane == 0) red_max[wv] = mx;
  __syncthreads();
  mx = fmaxf(fmaxf(red_max[0], red_max[1]), fmaxf(red_max[2], red_max[3]));

  float sum = 0.f;
#pragma unroll
  for (int i = 0; i < 8; ++i) {
    vals[i] = expf(vals[i] - mx);
    sum += vals[i];
  }
#pragma unroll
  for (int m = 32; m; m >>= 1) sum += __shfl_xor(sum, m, 64);
  if (lane == 0) red_sum[wv] = sum;
  __syncthreads();
  sum = red_sum[0] + red_sum[1] + red_sum[2] + red_sum[3];

  float inv = 1.0f / sum;
#pragma unroll
  for (int i = 0; i < 8; ++i) row[tid + i * 256] = vals[i] * inv;
}

extern "C" void kernel_launch(void* const* d_in, const int* in_sizes, int n_in,
                              void* d_out, int out_size, void* d_ws, size_t ws_size,
                              hipStream_t stream) {
  const float* enc = (const float*)d_in[0];   // (S,B,H)
  // d_in[1] rnn_hidden, d_in[3] attn_b: cancel under softmax (shift-invariant)
  const float* W = (const float*)d_in[2];     // (H, 2H)
  const float* v = (const float*)d_in[4];     // (1, H)
  float* out = (float*)d_out;                 // (B,1,S) = B*S floats

  float* u       = (float*)d_ws;              // 4 KB
  float* partial = (float*)d_ws + HH;         // 64 KB

  partial_u_kernel<<<dim3(4, 16), 256, 0, stream>>>(W, v, partial);
  reduce_u_kernel<<<4, 256, 0, stream>>>(partial, u);
  energy_kernel<<<(SS * BB) / 4, 256, 0, stream>>>(enc, u, out);
  softmax_kernel<<<BB, 256, 0, stream>>>(out);
}